// Round 12
// baseline (52864.618 us; speedup 1.0000x reference)
//
#include <hip/hip_runtime.h>

#define HID   1024
#define SEQT  8192
#define NBLK  512
#define TPB   256   // 4 waves: widx0,1 = L1 rows; widx2,3 = L2 rows

// ws (bytes): [0,16K) u64 h1t[2][1024] ; [16K,32K) u64 h2t[2][1024]
// packed slot: (tag<<32)|fp32_bits ; h(s) in slot s&1 with tag s+1; init 0
#define WS_BYTES 32768

typedef float v16f __attribute__((ext_vector_type(16)));
typedef _Float16 f16x2 __attribute__((ext_vector_type(2)));
typedef unsigned long long u64;

__device__ __forceinline__ float sig_(float x) { return 1.0f / (1.0f + expf(-x)); }

__device__ __forceinline__ u64 ldp(const u64* p) {
    return __hip_atomic_load(p, __ATOMIC_RELAXED, __HIP_MEMORY_SCOPE_AGENT);
}
__device__ __forceinline__ void stp(u64* p, u64 v) {
    __hip_atomic_store(p, v, __ATOMIC_RELAXED, __HIP_MEMORY_SCOPE_AGENT);
}

__device__ __forceinline__ f16x2 mk2(float a, float b) {
    f16x2 v; v[0] = (_Float16)a; v[1] = (_Float16)b; return v;
}

#if __has_builtin(__builtin_amdgcn_fdot2)
__device__ __forceinline__ float dot2(f16x2 a, f16x2 b, float c) {
    return __builtin_amdgcn_fdot2(a, b, c, false);   // v_dot2_f32_f16
}
#else
__device__ __forceinline__ float dot2(f16x2 a, f16x2 b, float c) {
    return c + (float)a[0] * (float)b[0] + (float)a[1] * (float)b[1];
}
#endif

extern "C" __global__ void __launch_bounds__(TPB, 2)
lstm_lds(const float* __restrict__ seq,
         const float* __restrict__ w_ih1, const float* __restrict__ w_hh1,
         const float* __restrict__ b_ih1, const float* __restrict__ b_hh1,
         const float* __restrict__ w_ih2, const float* __restrict__ w_hh2,
         const float* __restrict__ b_ih2, const float* __restrict__ b_hh2,
         const float* __restrict__ w_lin, const float* __restrict__ b_lin,
         float* __restrict__ out, u64* ws)
{
    // f16 weights, packed as half2 pairs (cols lane+128j, lane+128j+64):
    __shared__ f16x2 wA[4][4][8][64];   // [widx][gate][j][lane]  L1:w_hh1 / L2:w_ih2  32KB
    __shared__ f16x2 wB[2][4][8][64];   // [widx-2][gate][j][lane]         L2:w_hh2    16KB
    __shared__ f16x2 h1p[8][64];        // staged h1(t-1), f16 pairs                    2KB
    __shared__ f16x2 h2p[8][64];        // staged h2(t-2), f16 pairs                    2KB

    const int  lane = threadIdx.x & 63;
    const int  widx = threadIdx.x >> 6;        // 0..3
    const int  blk  = blockIdx.x;
    const bool isL1 = (widx < 2);
    const int  r    = blk * 2 + (widx & 1);    // owned hidden row 0..1023

    u64* h1t = ws;            // [2][1024]
    u64* h2t = ws + 2048;     // [2][1024]

    // ---- one-time weight load -> f16 LDS (per-wave private region) ----
    if (isL1) {
#pragma unroll
        for (int g = 0; g < 4; ++g) {
            const float* row = w_hh1 + (size_t)(g * HID + r) * HID;
#pragma unroll
            for (int j = 0; j < 8; ++j)
                wA[widx][g][j][lane] = mk2(row[lane + 128 * j], row[lane + 128 * j + 64]);
        }
    } else {
#pragma unroll
        for (int g = 0; g < 4; ++g) {
            const float* ri = w_ih2 + (size_t)(g * HID + r) * HID;
            const float* rh = w_hh2 + (size_t)(g * HID + r) * HID;
#pragma unroll
            for (int j = 0; j < 8; ++j) {
                wA[widx][g][j][lane]     = mk2(ri[lane + 128 * j], ri[lane + 128 * j + 64]);
                wB[widx - 2][g][j][lane] = mk2(rh[lane + 128 * j], rh[lane + 128 * j + 64]);
            }
        }
    }
    const float* bbi = isL1 ? b_ih1 : b_ih2;
    const float* bbh = isL1 ? b_hh1 : b_hh2;
    const float bb0 = bbi[0 * HID + r] + bbh[0 * HID + r];
    const float bb1 = bbi[1 * HID + r] + bbh[1 * HID + r];
    const float bb2 = bbi[2 * HID + r] + bbh[2 * HID + r];
    const float bb3 = bbi[3 * HID + r] + bbh[3 * HID + r];
    float wx0 = 0.f, wx1 = 0.f, wx2 = 0.f, wx3 = 0.f;
    if (isL1) {
        wx0 = w_ih1[0 * HID + r]; wx1 = w_ih1[1 * HID + r];
        wx2 = w_ih1[2 * HID + r]; wx3 = w_ih1[3 * HID + r];
    }

    const bool carrier = (blk == 0 && widx == 2);   // L2 poller of block 0
    v16f WL; float blin = 0.f;
#pragma unroll
    for (int k = 0; k < 16; ++k) WL[k] = 0.f;
    if (carrier) {
#pragma unroll
        for (int k = 0; k < 16; ++k) WL[k] = w_lin[lane + 64 * k];
        blin = b_lin[0];
    }

    u64* pub = isL1 ? h1t : h2t;
    float c = 0.f;
    v16f vq2;                      // widx2: f32 copy of polled h2 (carrier's out input)
#pragma unroll
    for (int k = 0; k < 16; ++k) vq2[k] = 0.f;

    // Lock-step schedule (round-9 skeleton, proven):
    //   t: L1 -> h1(t) [t<SEQT];  L2 -> h2(t-1) [1<=t<=SEQT];  OUT -> out(t-2) [t>=2]
    // widx0 polls h1(t-1) (slot (t+1)&1, tag>=t), stages f16 pairs -> h1p.
    // widx2 polls h2(t-2) (slot t&1, tag>=t-1) -> h2p (+ f32 copy vq2).
    // Overwrite safety: identical hb-chain argument as round 9 (publish at t
    // requires observing h2(t-2) full => all step-t-1 polls completed).
    for (int t = 0; t <= SEQT + 1; ++t) {
        const float xt = (isL1 && t < SEQT) ? seq[t] : 0.f;   // issue before poll

        if (widx == 0 && t <= SEQT) {
            const u64* p = h1t + ((t + 1) & 1) * HID + lane;
            int guard = 0;
            for (;;) {
                u64 q[16]; int mn = 0x7fffffff;
#pragma unroll
                for (int k = 0; k < 16; ++k) { q[k] = ldp(p + 64 * k); mn = min(mn, (int)(q[k] >> 32)); }
#pragma unroll
                for (int j = 0; j < 8; ++j)
                    h1p[j][lane] = mk2(__uint_as_float((unsigned)q[2 * j]),
                                       __uint_as_float((unsigned)q[2 * j + 1]));
                if (__all(mn >= t)) break;
                if (++guard > (1 << 13)) break;   // bounded failsafe
            }
        }
        if (widx == 2) {
            const u64* p = h2t + (t & 1) * HID + lane;
            const int thr = t - 1;
            int guard = 0;
            for (;;) {
                u64 q[16]; int mn = 0x7fffffff;
#pragma unroll
                for (int k = 0; k < 16; ++k) { q[k] = ldp(p + 64 * k); mn = min(mn, (int)(q[k] >> 32)); }
#pragma unroll
                for (int j = 0; j < 8; ++j)
                    h2p[j][lane] = mk2(__uint_as_float((unsigned)q[2 * j]),
                                       __uint_as_float((unsigned)q[2 * j + 1]));
#pragma unroll
                for (int k = 0; k < 16; ++k) vq2[k] = __uint_as_float((unsigned)q[k]);
                if (__all(mn >= thr)) break;
                if (++guard > (1 << 13)) break;
            }
        }
        __syncthreads();

        const bool act = isL1 ? (t < SEQT) : (t >= 1 && t <= SEQT);
        if (act) {
            float a0 = 0.f, a1 = 0.f, a2 = 0.f, a3 = 0.f;
#pragma unroll
            for (int j = 0; j < 8; ++j) {
                const f16x2 h = h1p[j][lane];
                a0 = dot2(wA[widx][0][j][lane], h, a0);
                a1 = dot2(wA[widx][1][j][lane], h, a1);
                a2 = dot2(wA[widx][2][j][lane], h, a2);
                a3 = dot2(wA[widx][3][j][lane], h, a3);
            }
            if (!isL1) {
#pragma unroll
                for (int j = 0; j < 8; ++j) {
                    const f16x2 h = h2p[j][lane];
                    a0 = dot2(wB[widx - 2][0][j][lane], h, a0);
                    a1 = dot2(wB[widx - 2][1][j][lane], h, a1);
                    a2 = dot2(wB[widx - 2][2][j][lane], h, a2);
                    a3 = dot2(wB[widx - 2][3][j][lane], h, a3);
                }
            }
#pragma unroll
            for (int s = 32; s; s >>= 1) {
                a0 += __shfl_xor(a0, s);
                a1 += __shfl_xor(a1, s);
                a2 += __shfl_xor(a2, s);
                a3 += __shfl_xor(a3, s);
            }
            if (lane == 0) {
                float gi = sig_(a0 + xt * wx0 + bb0);
                float gf = sig_(a1 + xt * wx1 + bb1);
                float gg = tanhf(a2 + xt * wx2 + bb2);
                float go = sig_(a3 + xt * wx3 + bb3);
                c = gf * c + gi * gg;
                float h = go * tanhf(c);
                const int ps = isL1 ? t : (t - 1);   // produced timestep
                stp(pub + (ps & 1) * HID + r,
                    ((u64)(unsigned)(ps + 1) << 32) | (u64)__float_as_uint(h));
            }
        }

        // out(t-2): carrier's own polled f32 values (exact, no f16 error)
        if (carrier && t >= 2) {
            float ov = 0.f;
#pragma unroll
            for (int k = 0; k < 16; ++k) ov = fmaf(WL[k], vq2[k], ov);
#pragma unroll
            for (int s = 32; s; s >>= 1) ov += __shfl_xor(ov, s);
            if (lane == 0) out[t - 2] = ov + blin;
        }

        __syncthreads();   // protect h1p/h2p from next step's restaging
    }
}

extern "C" void kernel_launch(void* const* d_in, const int* in_sizes, int n_in,
                              void* d_out, int out_size, void* d_ws, size_t ws_size,
                              hipStream_t stream)
{
    (void)hipMemsetAsync(d_ws, 0, WS_BYTES, stream);

    const float* seq  = (const float*)d_in[0];
    const float* wih1 = (const float*)d_in[1];
    const float* whh1 = (const float*)d_in[2];
    const float* bih1 = (const float*)d_in[3];
    const float* bhh1 = (const float*)d_in[4];
    const float* wih2 = (const float*)d_in[5];
    const float* whh2 = (const float*)d_in[6];
    const float* bih2 = (const float*)d_in[7];
    const float* bhh2 = (const float*)d_in[8];
    const float* wlin = (const float*)d_in[9];
    const float* blin = (const float*)d_in[10];
    float* out = (float*)d_out;
    u64*   ws  = (u64*)d_ws;

    hipLaunchKernelGGL(lstm_lds, dim3(NBLK), dim3(TPB), 0, stream,
                       seq, wih1, whh1, bih1, bhh1,
                       wih2, whh2, bih2, bhh2, wlin, blin,
                       out, ws);
}

// Round 13
// 37456.927 us; speedup vs baseline: 1.4113x; 1.4113x over previous
//
#include <hip/hip_runtime.h>

#define HID   1024
#define SEQT  8192
#define NBLK  256
#define TPB   512   // 8 waves: widx 0-3 = L1 rows, widx 4-7 = L2 rows

// ws (bytes): [0,16K) u64 h1t[2][1024] ; [16K,32K) u64 h2t[2][1024]
// packed slot: (tag<<32)|fp32_bits ; h(s) in slot s&1 with tag s+1; init 0
#define WS_BYTES 32768

typedef float v16f __attribute__((ext_vector_type(16)));
typedef _Float16 f16x2 __attribute__((ext_vector_type(2)));
typedef _Float16 f16x8 __attribute__((ext_vector_type(8)));
typedef unsigned long long u64;

__device__ __forceinline__ float sig_(float x) { return 1.0f / (1.0f + expf(-x)); }

__device__ __forceinline__ u64 ldp(const u64* p) {
    return __hip_atomic_load(p, __ATOMIC_RELAXED, __HIP_MEMORY_SCOPE_AGENT);
}
__device__ __forceinline__ void stp(u64* p, u64 v) {
    __hip_atomic_store(p, v, __ATOMIC_RELAXED, __HIP_MEMORY_SCOPE_AGENT);
}
__device__ __forceinline__ f16x2 mk2(float a, float b) {
    f16x2 v; v[0] = (_Float16)a; v[1] = (_Float16)b; return v;
}

#if __has_builtin(__builtin_amdgcn_fdot2)
__device__ __forceinline__ float dot2(f16x2 a, f16x2 b, float c) {
    return __builtin_amdgcn_fdot2(a, b, c, false);   // v_dot2_f32_f16
}
#else
__device__ __forceinline__ float dot2(f16x2 a, f16x2 b, float c) {
    return c + (float)a[0] * (float)b[0] + (float)a[1] * (float)b[1];
}
#endif

extern "C" __global__ void __launch_bounds__(TPB, 1)
lstm_lds9(const float* __restrict__ seq,
          const float* __restrict__ w_ih1, const float* __restrict__ w_hh1,
          const float* __restrict__ b_ih1, const float* __restrict__ b_hh1,
          const float* __restrict__ w_ih2, const float* __restrict__ w_hh2,
          const float* __restrict__ b_ih2, const float* __restrict__ b_hh2,
          const float* __restrict__ w_lin, const float* __restrict__ b_lin,
          float* __restrict__ out, u64* ws)
{
    // f16 weights in LDS. Per (widx, j, lane): one 16B word = 4 gates x f16x2
    // for column pair (lane+128j, lane+128j+64) -> one ds_read_b128 per j.
    __shared__ f16x8 wA[8][8][64];      // L1: w_hh1 | L2: w_ih2      64 KB
    __shared__ f16x8 wB[4][8][64];      // L2: w_hh2                  32 KB
    __shared__ f16x2 h1p[2][8][64];     // staged h1, dbuf by t&1      4 KB
    __shared__ f16x2 h2p[2][8][64];     // staged h2, dbuf by t&1      4 KB

    const int  lane = threadIdx.x & 63;
    const int  widx = threadIdx.x >> 6;        // 0..7
    const int  blk  = blockIdx.x;
    const bool isL1 = (widx < 4);
    const int  r    = blk * 4 + (widx & 3);    // owned hidden row

    u64* h1t = ws;            // [2][1024]
    u64* h2t = ws + 2048;     // [2][1024]

    // ---- one-time weight load -> f16 LDS ----
    if (isL1) {
#pragma unroll
        for (int j = 0; j < 8; ++j) {
            f16x8 w;
#pragma unroll
            for (int g = 0; g < 4; ++g) {
                const float* row = w_hh1 + (size_t)(g * HID + r) * HID;
                w[2 * g]     = (_Float16)row[lane + 128 * j];
                w[2 * g + 1] = (_Float16)row[lane + 128 * j + 64];
            }
            wA[widx][j][lane] = w;
        }
    } else {
#pragma unroll
        for (int j = 0; j < 8; ++j) {
            f16x8 wi, wh;
#pragma unroll
            for (int g = 0; g < 4; ++g) {
                const float* ri = w_ih2 + (size_t)(g * HID + r) * HID;
                const float* rh = w_hh2 + (size_t)(g * HID + r) * HID;
                wi[2 * g]     = (_Float16)ri[lane + 128 * j];
                wi[2 * g + 1] = (_Float16)ri[lane + 128 * j + 64];
                wh[2 * g]     = (_Float16)rh[lane + 128 * j];
                wh[2 * g + 1] = (_Float16)rh[lane + 128 * j + 64];
            }
            wA[widx][j][lane]     = wi;
            wB[widx - 4][j][lane] = wh;
        }
    }
    const float* bbi = isL1 ? b_ih1 : b_ih2;
    const float* bbh = isL1 ? b_hh1 : b_hh2;
    const float bb0 = bbi[0 * HID + r] + bbh[0 * HID + r];
    const float bb1 = bbi[1 * HID + r] + bbh[1 * HID + r];
    const float bb2 = bbi[2 * HID + r] + bbh[2 * HID + r];
    const float bb3 = bbi[3 * HID + r] + bbh[3 * HID + r];
    float wx0 = 0.f, wx1 = 0.f, wx2 = 0.f, wx3 = 0.f;
    if (isL1) {
        wx0 = w_ih1[0 * HID + r]; wx1 = w_ih1[1 * HID + r];
        wx2 = w_ih1[2 * HID + r]; wx3 = w_ih1[3 * HID + r];
    }

    const bool carrier = (blk == 0 && widx == 4);   // the h2 poller of block 0
    v16f WL; float blin = 0.f;
#pragma unroll
    for (int k = 0; k < 16; ++k) WL[k] = 0.f;
    if (carrier) {
#pragma unroll
        for (int k = 0; k < 16; ++k) WL[k] = w_lin[lane + 64 * k];
        blin = b_lin[0];
    }

    u64* pub = isL1 ? h1t : h2t;
    float c = 0.f;
    v16f vq2;                    // widx4: exact f32 copy of polled h2 (for out)
#pragma unroll
    for (int k = 0; k < 16; ++k) vq2[k] = 0.f;

    // Round-9 lock-step schedule, ONE barrier/step (dbuf LDS staging):
    //   t: L1 -> h1(t) [t<SEQT]; L2 -> h2(t-1) [1<=t<=SEQT]; OUT -> out(t-2) [t>=2]
    // Overwrite safety (global slots): publish(t) happens after this block's
    // poller saw h2(t-2) full => every block passed barrier(t-1) => no block
    // still reads h1(t-2)/h2(t-3). LDS dbuf safety: poller re-stages buffer
    // t&1 at step t+2 only after barrier(t+1) => all waves finished compute(t).
    for (int t = 0; t <= SEQT + 1; ++t) {
        const float xt = (isL1 && t < SEQT) ? seq[t] : 0.f;   // issue pre-poll
        const int cur = t & 1;

        if (widx == 0 && t <= SEQT) {
            // poll h1(t-1): slot (t+1)&1, tag >= t (t=0: init tag 0 passes)
            const u64* p = h1t + ((t + 1) & 1) * HID + lane;
            u64 q[16];
            int guard = 0;
            for (;;) {
                int mn = 0x7fffffff;
#pragma unroll
                for (int k = 0; k < 16; ++k) { q[k] = ldp(p + 64 * k); mn = min(mn, (int)(q[k] >> 32)); }
                if (__all(mn >= t)) break;
                if (++guard > (1 << 13)) break;   // bounded failsafe
            }
#pragma unroll
            for (int j = 0; j < 8; ++j)
                h1p[cur][j][lane] = mk2(__uint_as_float((unsigned)q[2 * j]),
                                        __uint_as_float((unsigned)q[2 * j + 1]));
        }
        if (widx == 4) {
            // poll h2(t-2): slot t&1, tag >= t-1 (t<=1: init tag 0 passes)
            const u64* p = h2t + cur * HID + lane;
            const int thr = t - 1;
            u64 q[16];
            int guard = 0;
            for (;;) {
                int mn = 0x7fffffff;
#pragma unroll
                for (int k = 0; k < 16; ++k) { q[k] = ldp(p + 64 * k); mn = min(mn, (int)(q[k] >> 32)); }
                if (__all(mn >= thr)) break;
                if (++guard > (1 << 13)) break;
            }
#pragma unroll
            for (int j = 0; j < 8; ++j)
                h2p[cur][j][lane] = mk2(__uint_as_float((unsigned)q[2 * j]),
                                        __uint_as_float((unsigned)q[2 * j + 1]));
#pragma unroll
            for (int k = 0; k < 16; ++k) vq2[k] = __uint_as_float((unsigned)q[k]);
        }
        __syncthreads();

        const bool act = isL1 ? (t < SEQT) : (t >= 1 && t <= SEQT);
        if (act) {
            float a0 = 0.f, a1 = 0.f, a2 = 0.f, a3 = 0.f;
#pragma unroll
            for (int j = 0; j < 8; ++j) {
                const f16x2 h = h1p[cur][j][lane];
                const f16x8 w = wA[widx][j][lane];
                f16x2 g0; g0[0] = w[0]; g0[1] = w[1];
                f16x2 g1; g1[0] = w[2]; g1[1] = w[3];
                f16x2 g2; g2[0] = w[4]; g2[1] = w[5];
                f16x2 g3; g3[0] = w[6]; g3[1] = w[7];
                a0 = dot2(g0, h, a0);
                a1 = dot2(g1, h, a1);
                a2 = dot2(g2, h, a2);
                a3 = dot2(g3, h, a3);
            }
            if (!isL1) {
#pragma unroll
                for (int j = 0; j < 8; ++j) {
                    const f16x2 h = h2p[cur][j][lane];
                    const f16x8 w = wB[widx - 4][j][lane];
                    f16x2 g0; g0[0] = w[0]; g0[1] = w[1];
                    f16x2 g1; g1[0] = w[2]; g1[1] = w[3];
                    f16x2 g2; g2[0] = w[4]; g2[1] = w[5];
                    f16x2 g3; g3[0] = w[6]; g3[1] = w[7];
                    a0 = dot2(g0, h, a0);
                    a1 = dot2(g1, h, a1);
                    a2 = dot2(g2, h, a2);
                    a3 = dot2(g3, h, a3);
                }
            }
#pragma unroll
            for (int s = 32; s; s >>= 1) {
                a0 += __shfl_xor(a0, s);
                a1 += __shfl_xor(a1, s);
                a2 += __shfl_xor(a2, s);
                a3 += __shfl_xor(a3, s);
            }
            if (lane == 0) {
                float gi = sig_(a0 + xt * wx0 + bb0);
                float gf = sig_(a1 + xt * wx1 + bb1);
                float gg = tanhf(a2 + xt * wx2 + bb2);
                float go = sig_(a3 + xt * wx3 + bb3);
                c = gf * c + gi * gg;
                float h = go * tanhf(c);
                const int ps = isL1 ? t : (t - 1);   // produced timestep
                stp(pub + (ps & 1) * HID + r,
                    ((u64)(unsigned)(ps + 1) << 32) | (u64)__float_as_uint(h));
            }
        }

        // out(t-2): carrier's own polled f32 values (exact, no f16 error)
        if (carrier && t >= 2) {
            float ov = 0.f;
#pragma unroll
            for (int k = 0; k < 16; ++k) ov = fmaf(WL[k], vq2[k], ov);
#pragma unroll
            for (int s = 32; s; s >>= 1) ov += __shfl_xor(ov, s);
            if (lane == 0) out[t - 2] = ov + blin;
        }
    }
}

extern "C" void kernel_launch(void* const* d_in, const int* in_sizes, int n_in,
                              void* d_out, int out_size, void* d_ws, size_t ws_size,
                              hipStream_t stream)
{
    (void)hipMemsetAsync(d_ws, 0, WS_BYTES, stream);

    const float* seq  = (const float*)d_in[0];
    const float* wih1 = (const float*)d_in[1];
    const float* whh1 = (const float*)d_in[2];
    const float* bih1 = (const float*)d_in[3];
    const float* bhh1 = (const float*)d_in[4];
    const float* wih2 = (const float*)d_in[5];
    const float* whh2 = (const float*)d_in[6];
    const float* bih2 = (const float*)d_in[7];
    const float* bhh2 = (const float*)d_in[8];
    const float* wlin = (const float*)d_in[9];
    const float* blin = (const float*)d_in[10];
    float* out = (float*)d_out;
    u64*   ws  = (u64*)d_ws;

    hipLaunchKernelGGL(lstm_lds9, dim3(NBLK), dim3(TPB), 0, stream,
                       seq, wih1, whh1, bih1, bhh1,
                       wih2, whh2, bih2, bhh2, wlin, blin,
                       out, ws);
}